// Round 12
// baseline (172.628 us; speedup 1.0000x reference)
//
#include <hip/hip_runtime.h>

#define HH 64
#define WW 64
#define S  68          // padded LDS row stride (floats)
#define PH 66          // padded rows (1-px zero frame)
#define NLQ 10
#define NP  5          // channel pairs
#define NR 8           // rows per thread (512 threads = 8 waves = 2/SIMD)

typedef float f32x2 __attribute__((ext_vector_type(2)));

// One block per image (grid=256 = 1 block/CU). Thread t: column x=t&63, rows
// y0..y0+7. Wave yg owns image rows y0..y0+7 (padded rows y0+1..y0+8).
//
// Session evidence (R1-R18): time is pinned at ~2.4us/step across FOUR
// different instruction streams (R12/R15/R17/R18 = 102-106us, VALUBusy
// 58-66%), while R1's 2x-bigger stream ran 110us at 104% busy. Conclusion:
// a ~5600cyc/step STRUCTURAL floor (lockstep __syncthreads: all 8 waves
// burst ~240 ds_reads onto the one LDS pipe, stall at the same waitcnt/
// barrier points, nothing overlaps). Instruction dieting cannot beat it.
//
// R19: break the lockstep. The only cross-wave dependency is the 1-row halo
// with yg+-1. Replace the 39 in-loop barriers with per-wave LDS flags +
// neighbor-only spin (producer-consumer):
//   - start step it when flg[yg-1] >= it-1 && flg[yg+1] >= it-1
//     (covers halo-publish AND ping-pong overwrite safety; max drift 1)
//   - set flg[yg] = it after step-it writes (+release fence)
//   - interior rows j=1..6 need only self-written rows -> computed BEFORE
//     the spin; only j=0 and j=7 wait for the halo.
// Waves drift out of phase -> LDS bursts and FMA blocks overlap across
// waves; barrier drains gone. Per-output fma order unchanged -> identical
// numerics.
__global__ __launch_bounds__(512)
__attribute__((amdgpu_waves_per_eu(2, 2)))
void vin_fused(
    const float* __restrict__ X,    // [B,2,64,64]
    const float* __restrict__ Wh,   // [150,2,3,3]
    const float* __restrict__ bh,   // [150]
    const float* __restrict__ Wr,   // [150]
    const float* __restrict__ Wq,   // [10,1,3,3]
    const float* __restrict__ wtr,  // [10,1,3,3] transition
    const float* __restrict__ Wc,   // [4096]
    const float* __restrict__ bc,   // [1]
    float* __restrict__ out)        // [256 critic] ++ [256*40960 q]
{
  __shared__ float vb[2][PH * S];
  __shared__ float rb[PH * S];
  __shared__ float Wef[19];
  __shared__ float Wpart[152];
  __shared__ float red[8];
  __shared__ int   flg[8];

  const int b  = blockIdx.x;
  const int t  = threadIdx.x;
  const int x  = t & 63;
  const int yg = t >> 6;
  const int y0 = yg * NR;
  const int base0 = y0 * S + x;   // padded row y0, col x (window top-left)

  volatile int* vflg = flg;

  // ---- zero LDS (frames must be 0; interiors overwritten); init flags ----
  {
    float* vbf = &vb[0][0];
    for (int i = t; i < 2 * PH * S; i += 512) vbf[i] = 0.f;
    for (int i = t; i < PH * S; i += 512) rb[i] = 0.f;
    if (t < 8) flg[t] = -1;
  }
  __syncthreads();

  // ---- stage X into vb interiors; collapse 150-ch conv to Wef[19] ----
  const float* Xb = X + (size_t)b * (2 * HH * WW);
  for (int i = t; i < HH * WW; i += 512) {
    const int yy = i >> 6, xx = i & 63;
    vb[0][(yy + 1) * S + xx + 1] = Xb[i];
    vb[1][(yy + 1) * S + xx + 1] = Xb[HH * WW + i];
  }
  if (t < 152) {                       // parallel collapse: 19 outputs x 8 parts
    const int i = t >> 3, part = t & 7;
    float s = 0.f;
    if (i < 18) {
      for (int c = part; c < 150; c += 8) s += Wr[c] * Wh[c * 18 + i];
    } else {
      for (int c = part; c < 150; c += 8) s += Wr[c] * bh[c];
    }
    Wpart[t] = s;
  }
  __syncthreads();
  if (t < 19) {
    float s = 0.f;
#pragma unroll
    for (int k = 0; k < 8; ++k) s += Wpart[t * 8 + k];
    Wef[t] = s;
  }
  __syncthreads();

  // ---- r = conv(X, Weff, pad=1) + beff -> rb ----
  {
    float We[19];
#pragma unroll
    for (int i = 0; i < 19; ++i) We[i] = Wef[i];
#pragma unroll
    for (int j = 0; j < NR; ++j) {
      const int tb = base0 + j * S;
      float s = We[18];
#pragma unroll
      for (int dy = 0; dy < 3; ++dy)
#pragma unroll
        for (int dx = 0; dx < 3; ++dx) {
          const int idx = tb + dy * S + dx;
          s = fmaf(vb[0][idx], We[dy * 3 + dx], s);
          s = fmaf(vb[1][idx], We[9 + dy * 3 + dx], s);
        }
      rb[tb + S + 1] = s;
    }
  }
  __syncthreads();

  // ---- q0 = conv(r, Wq, pad=1) -> q0p pairs; v_init = max_l q0 -> vb[0] ----
  f32x2 q0p[NR][NP];
  {
    float win[NR + 2][3];
#pragma unroll
    for (int rr = 0; rr < NR + 2; ++rr) {
      const int a = base0 + rr * S;
      win[rr][0] = rb[a];
      win[rr][1] = rb[a + 1];
      win[rr][2] = rb[a + 2];
    }
    f32x2 mm[NR];
#pragma unroll
    for (int p = 0; p < NP; ++p) {
      f32x2 w[9];
#pragma unroll
      for (int k = 0; k < 9; ++k)
        w[k] = (f32x2){ Wq[(2 * p) * 9 + k], Wq[(2 * p + 1) * 9 + k] };
#pragma unroll
      for (int j = 0; j < NR; ++j) {
        f32x2 acc = (f32x2){0.f, 0.f};
#pragma unroll
        for (int dy = 0; dy < 3; ++dy)
#pragma unroll
          for (int dx = 0; dx < 3; ++dx) {
            const float wv = win[j + dy][dx];
            acc = __builtin_elementwise_fma(w[dy * 3 + dx], (f32x2){wv, wv}, acc);
          }
        q0p[j][p] = acc;
        mm[j] = (p == 0) ? acc : __builtin_elementwise_max(mm[j], acc);
      }
    }
#pragma unroll
    for (int j = 0; j < NR; ++j)
      vb[0][base0 + (j + 1) * S + 1] = fmaxf(mm[j].x, mm[j].y);
  }
  __syncthreads();   // last full barrier before the flagged K-loop

  // ---- transition weight pairs (persistent) ----
  f32x2 wtp[NP][9];
#pragma unroll
  for (int p = 0; p < NP; ++p)
#pragma unroll
    for (int k = 0; k < 9; ++k)
      wtp[p][k] = (f32x2){ wtr[(2 * p) * 9 + k], wtr[(2 * p + 1) * 9 + k] };

  // ---- K-loop: flag-synced producer-consumer, interior-first ----
#pragma unroll 1
  for (int it = 0; it < 39; ++it) {
    const float* vin  = vb[it & 1];
    float*       vout = vb[(it + 1) & 1];

    // own rows (written by self at step it-1; no sync needed)
    float win[NR + 2][3];
#pragma unroll
    for (int rr = 1; rr <= 8; ++rr) {
      const int a = base0 + rr * S;
      win[rr][0] = vin[a];
      win[rr][1] = vin[a + 1];
      win[rr][2] = vin[a + 2];
    }

    f32x2 mm[NR];
    // interior rows j=1..6 (no halo dependency)
#pragma unroll
    for (int p = 0; p < NP; ++p) {
      f32x2 w[9];
#pragma unroll
      for (int k = 0; k < 9; ++k) w[k] = wtp[p][k];
#pragma unroll
      for (int j = 1; j <= 6; ++j) {
        f32x2 acc = q0p[j][p];
#pragma unroll
        for (int dy = 0; dy < 3; ++dy)
#pragma unroll
          for (int dx = 0; dx < 3; ++dx) {
            const float wv = win[j + dy][dx];
            acc = __builtin_elementwise_fma(w[dy * 3 + dx], (f32x2){wv, wv}, acc);
          }
        mm[j] = (p == 0) ? acc : __builtin_elementwise_max(mm[j], acc);
      }
    }

    // wait for neighbors to have completed step it-1 (publish + reuse safety)
    if (yg > 0) { while (vflg[yg - 1] < it - 1) {} }
    if (yg < 7) { while (vflg[yg + 1] < it - 1) {} }
    __threadfence_block();   // acquire: halo reads below stay below

    // halo rows (row y0-1 -> win[0]; row y0+8 -> win[9]; frames for edge yg)
    {
      const int a0 = base0;
      win[0][0] = vin[a0];
      win[0][1] = vin[a0 + 1];
      win[0][2] = vin[a0 + 2];
      const int a9 = base0 + 9 * S;
      win[9][0] = vin[a9];
      win[9][1] = vin[a9 + 1];
      win[9][2] = vin[a9 + 2];
    }

    // boundary rows j=0 and j=7
#pragma unroll
    for (int p = 0; p < NP; ++p) {
      f32x2 w[9];
#pragma unroll
      for (int k = 0; k < 9; ++k) w[k] = wtp[p][k];
      f32x2 acc0 = q0p[0][p];
      f32x2 acc7 = q0p[7][p];
#pragma unroll
      for (int dy = 0; dy < 3; ++dy)
#pragma unroll
        for (int dx = 0; dx < 3; ++dx) {
          const int k = dy * 3 + dx;
          const float w0 = win[dy][dx];
          acc0 = __builtin_elementwise_fma(w[k], (f32x2){w0, w0}, acc0);
          const float w7 = win[7 + dy][dx];
          acc7 = __builtin_elementwise_fma(w[k], (f32x2){w7, w7}, acc7);
        }
      mm[0] = (p == 0) ? acc0 : __builtin_elementwise_max(mm[0], acc0);
      mm[7] = (p == 0) ? acc7 : __builtin_elementwise_max(mm[7], acc7);
    }

    // write v(it+1) rows, then publish
#pragma unroll
    for (int j = 0; j < NR; ++j)
      vout[base0 + (j + 1) * S + 1] = fmaxf(mm[j].x, mm[j].y);
    __threadfence_block();   // release: data before flag
    if (x == 0) vflg[yg] = it;
  }

  // ---- final iteration (it=39): emit q + critic dot (reads vb[1]) ----
  if (yg > 0) { while (vflg[yg - 1] < 38) {} }
  if (yg < 7) { while (vflg[yg + 1] < 38) {} }
  __threadfence_block();

  float wcv[NR];
#pragma unroll
  for (int j = 0; j < NR; ++j) wcv[j] = Wc[(y0 + j) * WW + x];

  float* qo = out + 256 + (size_t)b * (NLQ * HH * WW) + y0 * WW + x;
  float acc_c = 0.f;
  {
    const float* vin = vb[1];
    float win[NR + 2][3];
#pragma unroll
    for (int rr = 0; rr < NR + 2; ++rr) {
      const int a = base0 + rr * S;
      win[rr][0] = vin[a];
      win[rr][1] = vin[a + 1];
      win[rr][2] = vin[a + 2];
    }
    f32x2 mm[NR];
#pragma unroll
    for (int p = 0; p < NP; ++p) {
      f32x2 w[9];
#pragma unroll
      for (int k = 0; k < 9; ++k) w[k] = wtp[p][k];
#pragma unroll
      for (int j = 0; j < NR; ++j) {
        f32x2 acc = q0p[j][p];
#pragma unroll
        for (int dy = 0; dy < 3; ++dy)
#pragma unroll
          for (int dx = 0; dx < 3; ++dx) {
            const float wv = win[j + dy][dx];
            acc = __builtin_elementwise_fma(w[dy * 3 + dx], (f32x2){wv, wv}, acc);
          }
        qo[(2 * p)     * (HH * WW) + j * WW] = acc.x;
        qo[(2 * p + 1) * (HH * WW) + j * WW] = acc.y;
        mm[j] = (p == 0) ? acc : __builtin_elementwise_max(mm[j], acc);
      }
    }
#pragma unroll
    for (int j = 0; j < NR; ++j)
      acc_c = fmaf(fmaxf(mm[j].x, mm[j].y), wcv[j], acc_c);
  }

  // ---- block-reduce critic ----
#pragma unroll
  for (int off = 32; off > 0; off >>= 1) acc_c += __shfl_down(acc_c, off);
  if (x == 0) red[yg] = acc_c;
  __syncthreads();
  if (t == 0) {
    float s = bc[0];
#pragma unroll
    for (int i = 0; i < 8; ++i) s += red[i];
    out[b] = s;
  }
}

extern "C" void kernel_launch(void* const* d_in, const int* in_sizes, int n_in,
                              void* d_out, int out_size, void* d_ws, size_t ws_size,
                              hipStream_t stream) {
  (void)n_in; (void)out_size; (void)d_ws; (void)ws_size;
  const float* X   = (const float*)d_in[0];
  const float* Wh  = (const float*)d_in[1];
  const float* bh  = (const float*)d_in[2];
  const float* Wr  = (const float*)d_in[3];
  const float* Wq  = (const float*)d_in[4];
  const float* wtr = (const float*)d_in[5];
  const float* Wc  = (const float*)d_in[6];
  const float* bc  = (const float*)d_in[7];
  float* out = (float*)d_out;

  const int B = in_sizes[0] / (2 * HH * WW);   // 256
  vin_fused<<<B, 512, 0, stream>>>(X, Wh, bh, Wr, Wq, wtr, Wc, bc, out);
}